// Round 9
// baseline (672.798 us; speedup 1.0000x reference)
//
#include <hip/hip_runtime.h>

#define NE 500000
#define NB 256
#define D  128
#define NT2 3907          // ceil(NE/128) 128-edge tiles (8 waves x 16 rows)
#define GMAIN 512         // grid for k_main (2 blocks/CU co-resident)
#define SPLIT 16          // chunks per graph in k_accum2
#define APAD 8            // stride (u32) so each atomic counter sits on its own 32B
#define SCHUNK 1954       // ceil(NE/256)

typedef __attribute__((ext_vector_type(8))) short bf16x8;
typedef __attribute__((ext_vector_type(4))) float f32x4;

__device__ __forceinline__ float lrelu(float x){ return x > 0.0f ? x : 0.01f * x; }

// f32 -> bf16 (round-to-nearest-even), header-free
__device__ __forceinline__ unsigned short f2bf(float f){
  unsigned u = __float_as_uint(f);
  unsigned rounding = 0x7fffu + ((u >> 16) & 1u);
  return (unsigned short)((u + rounding) >> 16);
}

// monotonic float<->uint encoding for atomicMax on signed floats
__device__ __forceinline__ unsigned encf(float f){
  unsigned u = __float_as_uint(f);
  return (u & 0x80000000u) ? ~u : (u | 0x80000000u);
}
__device__ __forceinline__ float decf(unsigned u){
  return (u & 0x80000000u) ? __uint_as_float(u & 0x7fffffffu) : __uint_as_float(~u);
}

__global__ void k_init(unsigned* gmax, float* gsum, unsigned* hist){
  int t = threadIdx.x;
  if (t < NB){ gmax[t*APAD] = 0u; gsum[t*APAD] = 0.0f; hist[t*APAD] = 0u; }
}

// k = lrelu(u@Wk + bk); qu = u@Wq[128:] + bq; vu = u@Wv[128:] + bv
__global__ void k_pre(const float* __restrict__ u,  const float* __restrict__ Wq,
                      const float* __restrict__ bq, const float* __restrict__ Wk,
                      const float* __restrict__ bk, const float* __restrict__ Wv,
                      const float* __restrict__ bv,
                      float* __restrict__ kT, float* __restrict__ qu, float* __restrict__ vu){
  __shared__ float us[D];
  int b = blockIdx.x, c = threadIdx.x;
  us[c] = u[b*D + c];
  __syncthreads();
  float ka = bk[c], qa = bq[c], va = bv[c];
  #pragma unroll 4
  for (int j = 0; j < D; ++j){
    float uv = us[j];
    ka += uv * Wk[j*D + c];
    qa += uv * Wq[(D + j)*D + c];
    va += uv * Wv[(D + j)*D + c];
  }
  kT[b*D + c] = lrelu(ka);
  qu[b*D + c] = qa;
  vu[b*D + c] = va;
}

// WqT/WvT[c][k] = bf16(W[k][c]) for k<128 (edge half of the weight)
__global__ void k_prew(const float* __restrict__ Wq, const float* __restrict__ Wv,
                       unsigned short* __restrict__ WqT, unsigned short* __restrict__ WvT){
  int c = blockIdx.x, k = threadIdx.x;
  WqT[c*D + k] = f2bf(Wq[k*D + c]);
  WvT[c*D + k] = f2bf(Wv[k*D + c]);
}

// weight tables -> LDS, 256B rows, 16B-chunk XOR swizzle (bank-conflict-free reads)
__device__ __forceinline__ void stage_weights(unsigned short* wt, const unsigned short* Wsrc,
                                              int tid, int nthr){
  const uint4* wsrc = (const uint4*)Wsrc;      // 128x128 bf16 = 2048 uint4
  for (int i = tid; i < 2048; i += nthr){
    int c = i >> 4, off = (i & 15) << 4;
    *(uint4*)((char*)wt + c*256 + (off ^ ((c & 7) << 4))) = wsrc[i];
  }
}

// Fused single pass over edges. 128-edge tiles, 8 waves x 16 rows, barrier-free loop.
// Sequential q-GEMM -> q-epilogue -> v-GEMM -> v-epilogue to halve live accumulators:
//   scores[e] = lrelu(edges[e]@Wq[:128] + qu[eb]) . k[eb] / sqrt(128)  (+ per-graph max/count)
//   vprime[e][m*8+n] = bf16(lrelu(edges[e]@Wv[:128] + vu[eb]))[col=16n+m]
__global__ __launch_bounds__(512, 4)
void k_main(const float* __restrict__ edges, const int* __restrict__ send,
            const int* __restrict__ batch, const unsigned short* __restrict__ WqT,
            const unsigned short* __restrict__ WvT, const float* __restrict__ qu,
            const float* __restrict__ vu, const float* __restrict__ kT,
            float* __restrict__ scores, int* __restrict__ ebArr,
            unsigned short* __restrict__ vprime, unsigned* gmax, unsigned* hist){
  __shared__ __align__(16) unsigned short wq[D * D];   // 32 KB
  __shared__ __align__(16) unsigned short wv[D * D];   // 32 KB
  __shared__ unsigned lmax[NB], lcnt[NB];

  const int tid = threadIdx.x;
  stage_weights(wq, WqT, tid, 512);
  stage_weights(wv, WvT, tid, 512);
  if (tid < NB){ lmax[tid] = 0u; lcnt[tid] = 0u; }
  __syncthreads();      // weights + stats ready; no barriers after this

  const int lane = tid & 63, w = tid >> 6;
  const int g = lane >> 4, m = lane & 15;

  for (long tb = blockIdx.x; tb < NT2; tb += GMAIN){
    const long base = tb * 128 + (long)w * 16;   // this wave's 16 rows
    // graph ids for my rows (lanes 0-15), broadcast via shfl
    int ebm = 0;
    if (lane < 16){
      long e = base + lane; long ec = e < NE ? e : NE - 1;
      ebm = batch[send[ec]];
      if (e < NE) ebArr[e] = ebm;
    }
    int ebj[4];
    #pragma unroll
    for (int j = 0; j < 4; ++j) ebj[j] = __shfl(ebm, 4*g + j);

    // A-fragments: cached f32 loads, converted immediately to bf16 (frees f32 regs)
    long ar = base + m; if (ar >= NE) ar = NE - 1;
    const f32x4* ap = (const f32x4*)(edges + (size_t)ar * D);
    bf16x8 af[4];
    #pragma unroll
    for (int ks = 0; ks < 4; ++ks){
      f32x4 a = ap[ks*8 + g*2];
      f32x4 b = ap[ks*8 + g*2 + 1];
      af[ks][0] = (short)f2bf(a[0]); af[ks][1] = (short)f2bf(a[1]);
      af[ks][2] = (short)f2bf(a[2]); af[ks][3] = (short)f2bf(a[3]);
      af[ks][4] = (short)f2bf(b[0]); af[ks][5] = (short)f2bf(b[1]);
      af[ks][6] = (short)f2bf(b[2]); af[ks][7] = (short)f2bf(b[3]);
    }

    // ---- q-GEMM ----
    f32x4 acc[8];
    #pragma unroll
    for (int n = 0; n < 8; ++n)
      #pragma unroll
      for (int j = 0; j < 4; ++j) acc[n][j] = 0.0f;
    #pragma unroll
    for (int ks = 0; ks < 4; ++ks){
      int koff = ks*64 + (g << 4);
      #pragma unroll
      for (int n = 0; n < 8; ++n){
        int bc = 16*n + m, boff = koff ^ ((bc & 7) << 4);
        bf16x8 bqf = *(const bf16x8*)((const char*)wq + bc*256 + boff);
        acc[n] = __builtin_amdgcn_mfma_f32_16x16x32_bf16(af[ks], bqf, acc[n], 0, 0, 0);
      }
    }
    // q-epilogue: bias, dot with k[eb], reduce over m-bits, score store + stats
    #pragma unroll
    for (int j = 0; j < 4; ++j){
      long e = base + 4*g + j;
      const float* qrow = qu + (size_t)ebj[j] * D;
      const float* krow = kT + (size_t)ebj[j] * D;
      float p = 0.0f;
      #pragma unroll
      for (int n = 0; n < 8; ++n)
        p += lrelu(acc[n][j] + qrow[16*n + m]) * krow[16*n + m];
      p += __shfl_xor(p, 1); p += __shfl_xor(p, 2);
      p += __shfl_xor(p, 4); p += __shfl_xor(p, 8);
      if (m == 0 && e < NE){
        float sc = p * 0.08838834764831843f; // 1/sqrt(128)
        scores[e] = sc;
        atomicMax(&lmax[ebj[j]], encf(sc));
        atomicAdd(&lcnt[ebj[j]], 1u);
      }
    }

    // ---- v-GEMM (reuses acc registers) ----
    #pragma unroll
    for (int n = 0; n < 8; ++n)
      #pragma unroll
      for (int j = 0; j < 4; ++j) acc[n][j] = 0.0f;
    #pragma unroll
    for (int ks = 0; ks < 4; ++ks){
      int koff = ks*64 + (g << 4);
      #pragma unroll
      for (int n = 0; n < 8; ++n){
        int bc = 16*n + m, boff = koff ^ ((bc & 7) << 4);
        bf16x8 bvf = *(const bf16x8*)((const char*)wv + bc*256 + boff);
        acc[n] = __builtin_amdgcn_mfma_f32_16x16x32_bf16(af[ks], bvf, acc[n], 0, 0, 0);
      }
    }
    // v-epilogue: bias + lrelu + bf16 pack, 16B coalesced store
    #pragma unroll
    for (int j = 0; j < 4; ++j){
      long e = base + 4*g + j;
      const float* vrow = vu + (size_t)ebj[j] * D;
      bf16x8 pk;
      #pragma unroll
      for (int n = 0; n < 8; ++n)
        pk[n] = (short)f2bf(lrelu(acc[n][j] + vrow[16*n + m]));
      if (e < NE) *(bf16x8*)(vprime + (size_t)e * D + m*8) = pk;
    }
  }
  __syncthreads();
  if (tid < NB){
    unsigned c = lcnt[tid];
    if (c){ atomicAdd(&hist[tid*APAD], c); atomicMax(&gmax[tid*APAD], lmax[tid]); }
  }
}

__global__ void k_scan(const unsigned* __restrict__ hist, unsigned* __restrict__ offs,
                       unsigned* cursor){
  __shared__ unsigned sh[NB];
  __shared__ unsigned so[NB + 1];
  int tid = threadIdx.x;
  sh[tid] = hist[tid*APAD];
  __syncthreads();
  if (tid == 0){
    unsigned run = 0;
    for (int b = 0; b < NB; ++b){ so[b] = run; run += sh[b]; }
    so[NB] = run;
  }
  __syncthreads();
  offs[tid] = so[tid];
  cursor[tid*APAD] = so[tid];
  if (tid == 0) offs[NB] = so[NB];
}

// counting-sort scatter (block-batched) + per-graph sum of exp(score - max)
__global__ __launch_bounds__(256)
void k_scatter(const float* __restrict__ scores, const int* __restrict__ ebArr,
               const unsigned* __restrict__ gmax, unsigned* cursor,
               unsigned* __restrict__ perm, float* gsum){
  __shared__ unsigned lbase[NB];
  __shared__ unsigned lcnt[NB];
  __shared__ float lsum[NB];
  __shared__ float lgm[NB];
  int tid = threadIdx.x;
  lcnt[tid] = 0u; lsum[tid] = 0.0f; lgm[tid] = decf(gmax[tid*APAD]);
  __syncthreads();
  int start = blockIdx.x * SCHUNK;
  int end = start + SCHUNK; if (end > NE) end = NE;
  for (int e = start + tid; e < end; e += 256)
    atomicAdd(&lcnt[ebArr[e]], 1u);
  __syncthreads();
  unsigned c = lcnt[tid];
  lbase[tid] = c ? atomicAdd(&cursor[tid*APAD], c) : 0u;
  lcnt[tid] = 0u;
  __syncthreads();
  for (int e = start + tid; e < end; e += 256){
    int b = ebArr[e];
    unsigned p = lbase[b] + atomicAdd(&lcnt[b], 1u);
    perm[p] = (unsigned)e;
    atomicAdd(&lsum[b], __expf(scores[e] - lgm[b]));
  }
  __syncthreads();
  if (lsum[tid] != 0.0f) atomicAdd(&gsum[tid*APAD], lsum[tid]);
}

// per-(graph,chunk): weighted sum of bf16 v' rows (no GEMM) -> xpart in pos space
__global__ __launch_bounds__(256)
void k_accum2(const unsigned* __restrict__ vp32, const float* __restrict__ scores,
              const unsigned* __restrict__ gmax, const unsigned* __restrict__ offs,
              const unsigned* __restrict__ perm, float* __restrict__ xpart){
  __shared__ float xred[4 * D];
  const int tid = threadIdx.x;
  const int b = blockIdx.x >> 4, chunk = blockIdx.x & (SPLIT - 1);
  const unsigned o0 = offs[b];
  const int count = (int)(offs[b + 1] - o0);
  const int r0 = (int)(((long)count * chunk) / SPLIT);
  const int r1 = (int)(((long)count * (chunk + 1)) / SPLIT);
  const float gm = decf(gmax[b*APAD]);
  const int lane = tid & 63, w = tid >> 6;
  float xa = 0.0f, xb = 0.0f;
  #pragma unroll 4
  for (int i = r0 + w; i < r1; i += 4){
    unsigned e = perm[o0 + i];                       // wave-broadcast load
    float we = __expf(scores[e] - gm);
    unsigned d = vp32[(size_t)e * 64 + lane];        // 256B coalesced row
    xa += we * __uint_as_float(d << 16);
    xb += we * __uint_as_float(d & 0xffff0000u);
  }
  xred[w * D + 2*lane]     = xa;
  xred[w * D + 2*lane + 1] = xb;
  __syncthreads();
  if (tid < D){
    float s = xred[tid] + xred[D + tid] + xred[2*D + tid] + xred[3*D + tid];
    xpart[((size_t)b * SPLIT + chunk) * D + tid] = s;
  }
}

// sum chunks, /gsum, unpermute pos->col, then x@Wl + bl with lrelu
__global__ void k_final(const float* __restrict__ xpart, const float* __restrict__ gsum,
                        const float* __restrict__ Wl, const float* __restrict__ bl,
                        float* __restrict__ out){
  __shared__ float xr[D];     // in pos space
  int b = blockIdx.x, c = threadIdx.x;
  float gs = gsum[b*APAD];
  float s = 0.0f;
  #pragma unroll
  for (int ch = 0; ch < SPLIT; ++ch) s += xpart[((size_t)b * SPLIT + ch) * D + c];
  xr[c] = gs > 0.0f ? s / gs : 0.0f;
  __syncthreads();
  float a = bl[c];
  #pragma unroll 4
  for (int j = 0; j < D; ++j){
    float xv = xr[((j & 15) << 3) + (j >> 4)];   // pos = (col&15)*8 + (col>>4)
    a += xv * Wl[j*D + c];
  }
  out[(size_t)b * D + c] = lrelu(a);
}

extern "C" void kernel_launch(void* const* d_in, const int* in_sizes, int n_in,
                              void* d_out, int out_size, void* d_ws, size_t ws_size,
                              hipStream_t stream){
  // setup_inputs order: nodes, edges, edge_index, u, batch, Wq, bq, Wk, bk, Wv, bv, Wl, bl
  const float* edges = (const float*)d_in[1];
  const int*   send  = (const int*)d_in[2];      // edge_index[0] = first NE ints
  const float* u     = (const float*)d_in[3];
  const int*   batch = (const int*)d_in[4];
  const float* Wq    = (const float*)d_in[5];
  const float* bq    = (const float*)d_in[6];
  const float* Wk    = (const float*)d_in[7];
  const float* bk    = (const float*)d_in[8];
  const float* Wv    = (const float*)d_in[9];
  const float* bv    = (const float*)d_in[10];
  const float* Wl    = (const float*)d_in[11];
  const float* bl    = (const float*)d_in[12];
  float* out = (float*)d_out;

  char* wsb = (char*)d_ws;
  size_t off = 0;
  auto alloc = [&](size_t bytes)->char*{
    char* p = wsb + off; off += (bytes + 255) & ~(size_t)255; return p;
  };
  float*    kT     = (float*)   alloc((size_t)NB * D * 4);
  float*    qu     = (float*)   alloc((size_t)NB * D * 4);
  float*    vu     = (float*)   alloc((size_t)NB * D * 4);
  unsigned* gmax   = (unsigned*)alloc((size_t)NB * APAD * 4);
  float*    gsum   = (float*)   alloc((size_t)NB * APAD * 4);
  unsigned* hist   = (unsigned*)alloc((size_t)NB * APAD * 4);
  unsigned* cursor = (unsigned*)alloc((size_t)NB * APAD * 4);
  unsigned* offs   = (unsigned*)alloc((size_t)(NB + 1) * 4);
  unsigned short* WqTb = (unsigned short*)alloc((size_t)D * D * 2);
  unsigned short* WvTb = (unsigned short*)alloc((size_t)D * D * 2);
  float*    xpart  = (float*)   alloc((size_t)NB * SPLIT * D * 4);
  float*    scores = (float*)   alloc((size_t)NE * 4);
  int*      ebArr  = (int*)     alloc((size_t)NE * 4);
  unsigned* perm   = (unsigned*)alloc((size_t)NE * 4);
  unsigned short* vprime = (unsigned short*)alloc((size_t)NE * D * 2);  // 128 MB
  (void)ws_size; (void)in_sizes; (void)n_in; (void)out_size;

  k_init   <<<1, 256, 0, stream>>>(gmax, gsum, hist);
  k_pre    <<<NB, D, 0, stream>>>(u, Wq, bq, Wk, bk, Wv, bv, kT, qu, vu);
  k_prew   <<<D, D, 0, stream>>>(Wq, Wv, WqTb, WvTb);
  k_main   <<<GMAIN, 512, 0, stream>>>(edges, send, batch, WqTb, WvTb, qu, vu, kT,
                                       scores, ebArr, vprime, gmax, hist);
  k_scan   <<<1, 256, 0, stream>>>(hist, offs, cursor);
  k_scatter<<<256, 256, 0, stream>>>(scores, ebArr, gmax, cursor, perm, gsum);
  k_accum2 <<<NB * SPLIT, 256, 0, stream>>>((const unsigned*)vprime, scores, gmax, offs, perm, xpart);
  k_final  <<<NB, D, 0, stream>>>(xpart, gsum, Wl, bl, out);
}

// Round 10
// 235.448 us; speedup vs baseline: 2.8575x; 2.8575x over previous
//
#include <hip/hip_runtime.h>

#define NE 500000
#define NB 256
#define D  128
#define NT 7813           // ceil(NE/64) 64-edge tiles (4 waves x 16 rows)
#define GMAIN 512         // grid for k_main (2 blocks/CU co-resident)
#define SPLIT 16          // chunks per graph in k_accum2
#define APAD 8            // stride (u32) so each atomic counter sits on its own 32B
#define SCHUNK 1954       // ceil(NE/256)

typedef __attribute__((ext_vector_type(8))) short bf16x8;
typedef __attribute__((ext_vector_type(4))) float f32x4;

__device__ __forceinline__ float lrelu(float x){ return x > 0.0f ? x : 0.01f * x; }

// f32 -> bf16 (round-to-nearest-even), header-free
__device__ __forceinline__ unsigned short f2bf(float f){
  unsigned u = __float_as_uint(f);
  unsigned rounding = 0x7fffu + ((u >> 16) & 1u);
  return (unsigned short)((u + rounding) >> 16);
}

// monotonic float<->uint encoding for atomicMax on signed floats
__device__ __forceinline__ unsigned encf(float f){
  unsigned u = __float_as_uint(f);
  return (u & 0x80000000u) ? ~u : (u | 0x80000000u);
}
__device__ __forceinline__ float decf(unsigned u){
  return (u & 0x80000000u) ? __uint_as_float(u & 0x7fffffffu) : __uint_as_float(~u);
}

__global__ void k_init(unsigned* gmax, float* gsum, unsigned* hist){
  int t = threadIdx.x;
  if (t < NB){ gmax[t*APAD] = 0u; gsum[t*APAD] = 0.0f; hist[t*APAD] = 0u; }
}

// k = lrelu(u@Wk + bk); qu = u@Wq[128:] + bq; vu = u@Wv[128:] + bv
__global__ void k_pre(const float* __restrict__ u,  const float* __restrict__ Wq,
                      const float* __restrict__ bq, const float* __restrict__ Wk,
                      const float* __restrict__ bk, const float* __restrict__ Wv,
                      const float* __restrict__ bv,
                      float* __restrict__ kT, float* __restrict__ qu, float* __restrict__ vu){
  __shared__ float us[D];
  int b = blockIdx.x, c = threadIdx.x;
  us[c] = u[b*D + c];
  __syncthreads();
  float ka = bk[c], qa = bq[c], va = bv[c];
  #pragma unroll 4
  for (int j = 0; j < D; ++j){
    float uv = us[j];
    ka += uv * Wk[j*D + c];
    qa += uv * Wq[(D + j)*D + c];
    va += uv * Wv[(D + j)*D + c];
  }
  kT[b*D + c] = lrelu(ka);
  qu[b*D + c] = qa;
  vu[b*D + c] = va;
}

// WqT/WvT[c][k] = bf16(W[k][c]) for k<128 (edge half of the weight)
__global__ void k_prew(const float* __restrict__ Wq, const float* __restrict__ Wv,
                       unsigned short* __restrict__ WqT, unsigned short* __restrict__ WvT){
  int c = blockIdx.x, k = threadIdx.x;
  WqT[c*D + k] = f2bf(Wq[k*D + c]);
  WvT[c*D + k] = f2bf(Wv[k*D + c]);
}

// weight tables -> LDS, 256B rows, 16B-chunk XOR swizzle (bank-conflict-free reads)
__device__ __forceinline__ void stage_weights(unsigned short* wt, const unsigned short* Wsrc,
                                              int tid, int nthr){
  const uint4* wsrc = (const uint4*)Wsrc;      // 128x128 bf16 = 2048 uint4
  for (int i = tid; i < 2048; i += nthr){
    int c = i >> 4, off = (i & 15) << 4;
    *(uint4*)((char*)wt + c*256 + (off ^ ((c & 7) << 4))) = wsrc[i];
  }
}

// Fused single pass over edges. 64-edge LDS tiles (per-lane-contiguous 128B global
// reads -> bf16 -> swizzled LDS), both GEMMs per tile with LDS-resident weights:
//   scores[e] = lrelu(edges[e]@Wq[:128] + qu[eb]) . k[eb] / sqrt(128)
//   vprime[e][m*8+n] = bf16(lrelu(edges[e]@Wv[:128] + vu[eb]))[col=16n+m]
__global__ __launch_bounds__(256, 2)
void k_main(const float* __restrict__ edges, const int* __restrict__ send,
            const int* __restrict__ batch, const unsigned short* __restrict__ WqT,
            const unsigned short* __restrict__ WvT, const float* __restrict__ qu,
            const float* __restrict__ vu, const float* __restrict__ kT,
            float* __restrict__ scores, int* __restrict__ ebArr,
            unsigned short* __restrict__ vprime){
  __shared__ __align__(16) unsigned short wq[D * D];   // 32 KB
  __shared__ __align__(16) unsigned short wv[D * D];   // 32 KB
  __shared__ __align__(16) unsigned short xs[64 * D];  // 16 KB  (total 80 KB)

  const int tid = threadIdx.x;
  stage_weights(wq, WqT, tid, 256);
  stage_weights(wv, WvT, tid, 256);

  const int lane = tid & 63, w = tid >> 6;
  const int g = lane >> 4, m = lane & 15;
  const int r = tid >> 2, q = tid & 3;   // staging: 4 threads/row, 128B contiguous each

  for (long tb = blockIdx.x; tb < NT; tb += GMAIN){
    const long rowbase = tb * 64;
    // graph ids for my wave's 16 rows (lanes 0-15), broadcast via shfl
    int ebm = 0;
    if (lane < 16){
      long e = rowbase + w*16 + lane; long ec = e < NE ? e : NE - 1;
      ebm = batch[send[ec]];
      if (e < NE) ebArr[e] = ebm;
    }
    int ebj[4];
    #pragma unroll
    for (int j = 0; j < 4; ++j) ebj[j] = __shfl(ebm, 4*g + j);

    // stage 64 rows: per-lane 128B contiguous f32 (proven no-overfetch pattern)
    {
      long e = rowbase + r; long ec = e < NE ? e : NE - 1;
      const f32x4* src = (const f32x4*)(edges + (size_t)ec * D + q * 32);
      char* xrow = (char*)xs + r * 256;
      #pragma unroll
      for (int ci = 0; ci < 4; ++ci){
        f32x4 a = src[2*ci], b = src[2*ci + 1];
        bf16x8 pk;
        pk[0] = (short)f2bf(a[0]); pk[1] = (short)f2bf(a[1]);
        pk[2] = (short)f2bf(a[2]); pk[3] = (short)f2bf(a[3]);
        pk[4] = (short)f2bf(b[0]); pk[5] = (short)f2bf(b[1]);
        pk[6] = (short)f2bf(b[2]); pk[7] = (short)f2bf(b[3]);
        int off = q * 64 + ci * 16;
        *(bf16x8*)(xrow + (off ^ ((r & 7) << 4))) = pk;
      }
    }
    __syncthreads();   // xs + (first iter) weights ready

    // A-fragments for my 16 rows
    const int arow = w*16 + m;
    bf16x8 af[4];
    #pragma unroll
    for (int ks = 0; ks < 4; ++ks)
      af[ks] = *(const bf16x8*)((const char*)xs + arow*256 + ((ks*64 + (g<<4)) ^ ((arow & 7) << 4)));

    // ---- q-GEMM ----
    f32x4 acc[8];
    #pragma unroll
    for (int n = 0; n < 8; ++n)
      #pragma unroll
      for (int j = 0; j < 4; ++j) acc[n][j] = 0.0f;
    #pragma unroll
    for (int ks = 0; ks < 4; ++ks){
      int koff = ks*64 + (g << 4);
      #pragma unroll
      for (int n = 0; n < 8; ++n){
        int bc = 16*n + m, boff = koff ^ ((bc & 7) << 4);
        bf16x8 bqf = *(const bf16x8*)((const char*)wq + bc*256 + boff);
        acc[n] = __builtin_amdgcn_mfma_f32_16x16x32_bf16(af[ks], bqf, acc[n], 0, 0, 0);
      }
    }
    // q-epilogue: bias, dot with k[eb], reduce over m-bits
    #pragma unroll
    for (int j = 0; j < 4; ++j){
      long e = rowbase + w*16 + 4*g + j;
      const float* qrow = qu + (size_t)ebj[j] * D;
      const float* krow = kT + (size_t)ebj[j] * D;
      float p = 0.0f;
      #pragma unroll
      for (int n = 0; n < 8; ++n)
        p += lrelu(acc[n][j] + qrow[16*n + m]) * krow[16*n + m];
      p += __shfl_xor(p, 1); p += __shfl_xor(p, 2);
      p += __shfl_xor(p, 4); p += __shfl_xor(p, 8);
      if (m == 0 && e < NE) scores[e] = p * 0.08838834764831843f; // 1/sqrt(128)
    }

    // ---- v-GEMM (reuses acc) ----
    #pragma unroll
    for (int n = 0; n < 8; ++n)
      #pragma unroll
      for (int j = 0; j < 4; ++j) acc[n][j] = 0.0f;
    #pragma unroll
    for (int ks = 0; ks < 4; ++ks){
      int koff = ks*64 + (g << 4);
      #pragma unroll
      for (int n = 0; n < 8; ++n){
        int bc = 16*n + m, boff = koff ^ ((bc & 7) << 4);
        bf16x8 bvf = *(const bf16x8*)((const char*)wv + bc*256 + boff);
        acc[n] = __builtin_amdgcn_mfma_f32_16x16x32_bf16(af[ks], bvf, acc[n], 0, 0, 0);
      }
    }
    // v-epilogue: bias + lrelu + bf16 pack, 16B coalesced store
    #pragma unroll
    for (int j = 0; j < 4; ++j){
      long e = rowbase + w*16 + 4*g + j;
      const float* vrow = vu + (size_t)ebj[j] * D;
      bf16x8 pk;
      #pragma unroll
      for (int n = 0; n < 8; ++n)
        pk[n] = (short)f2bf(lrelu(acc[n][j] + vrow[16*n + m]));
      if (e < NE) *(bf16x8*)(vprime + (size_t)e * D + m*8) = pk;
    }
    __syncthreads();   // xs fully consumed before next stage
  }
}

// per-graph max + count (LDS pre-aggregation)
__global__ __launch_bounds__(256)
void k_stats(const float* __restrict__ scores, const int* __restrict__ ebArr,
             unsigned* gmax, unsigned* hist){
  __shared__ unsigned lmax[NB];
  __shared__ unsigned lcnt[NB];
  int tid = threadIdx.x;
  lmax[tid] = 0u; lcnt[tid] = 0u;
  __syncthreads();
  int start = blockIdx.x * SCHUNK;
  int end = start + SCHUNK; if (end > NE) end = NE;
  for (int e = start + tid; e < end; e += 256){
    int b = ebArr[e];
    atomicMax(&lmax[b], encf(scores[e]));
    atomicAdd(&lcnt[b], 1u);
  }
  __syncthreads();
  unsigned c = lcnt[tid];
  if (c){ atomicAdd(&hist[tid*APAD], c); atomicMax(&gmax[tid*APAD], lmax[tid]); }
}

__global__ void k_scan(const unsigned* __restrict__ hist, unsigned* __restrict__ offs,
                       unsigned* cursor){
  __shared__ unsigned sh[NB];
  __shared__ unsigned so[NB + 1];
  int tid = threadIdx.x;
  sh[tid] = hist[tid*APAD];
  __syncthreads();
  if (tid == 0){
    unsigned run = 0;
    for (int b = 0; b < NB; ++b){ so[b] = run; run += sh[b]; }
    so[NB] = run;
  }
  __syncthreads();
  offs[tid] = so[tid];
  cursor[tid*APAD] = so[tid];
  if (tid == 0) offs[NB] = so[NB];
}

// counting-sort scatter (block-batched) + per-graph sum of exp(score - max)
__global__ __launch_bounds__(256)
void k_scatter(const float* __restrict__ scores, const int* __restrict__ ebArr,
               const unsigned* __restrict__ gmax, unsigned* cursor,
               unsigned* __restrict__ perm, float* gsum){
  __shared__ unsigned lbase[NB];
  __shared__ unsigned lcnt[NB];
  __shared__ float lsum[NB];
  __shared__ float lgm[NB];
  int tid = threadIdx.x;
  lcnt[tid] = 0u; lsum[tid] = 0.0f; lgm[tid] = decf(gmax[tid*APAD]);
  __syncthreads();
  int start = blockIdx.x * SCHUNK;
  int end = start + SCHUNK; if (end > NE) end = NE;
  for (int e = start + tid; e < end; e += 256)
    atomicAdd(&lcnt[ebArr[e]], 1u);
  __syncthreads();
  unsigned c = lcnt[tid];
  lbase[tid] = c ? atomicAdd(&cursor[tid*APAD], c) : 0u;
  lcnt[tid] = 0u;
  __syncthreads();
  for (int e = start + tid; e < end; e += 256){
    int b = ebArr[e];
    unsigned p = lbase[b] + atomicAdd(&lcnt[b], 1u);
    perm[p] = (unsigned)e;
    atomicAdd(&lsum[b], __expf(scores[e] - lgm[b]));
  }
  __syncthreads();
  if (lsum[tid] != 0.0f) atomicAdd(&gsum[tid*APAD], lsum[tid]);
}

// per-(graph,chunk): weighted sum of bf16 v' rows (no GEMM) -> xpart in pos space
__global__ __launch_bounds__(256)
void k_accum2(const unsigned* __restrict__ vp32, const float* __restrict__ scores,
              const unsigned* __restrict__ gmax, const unsigned* __restrict__ offs,
              const unsigned* __restrict__ perm, float* __restrict__ xpart){
  __shared__ float xred[4 * D];
  const int tid = threadIdx.x;
  const int b = blockIdx.x >> 4, chunk = blockIdx.x & (SPLIT - 1);
  const unsigned o0 = offs[b];
  const int count = (int)(offs[b + 1] - o0);
  const int r0 = (int)(((long)count * chunk) / SPLIT);
  const int r1 = (int)(((long)count * (chunk + 1)) / SPLIT);
  const float gm = decf(gmax[b*APAD]);
  const int lane = tid & 63, w = tid >> 6;
  float xa = 0.0f, xb = 0.0f;
  #pragma unroll 4
  for (int i = r0 + w; i < r1; i += 4){
    unsigned e = perm[o0 + i];                       // wave-broadcast load
    float we = __expf(scores[e] - gm);
    unsigned d = vp32[(size_t)e * 64 + lane];        // 256B coalesced row
    xa += we * __uint_as_float(d << 16);
    xb += we * __uint_as_float(d & 0xffff0000u);
  }
  xred[w * D + 2*lane]     = xa;
  xred[w * D + 2*lane + 1] = xb;
  __syncthreads();
  if (tid < D){
    float s = xred[tid] + xred[D + tid] + xred[2*D + tid] + xred[3*D + tid];
    xpart[((size_t)b * SPLIT + chunk) * D + tid] = s;
  }
}

// sum chunks, /gsum, unpermute pos->col, then x@Wl + bl with lrelu
__global__ void k_final(const float* __restrict__ xpart, const float* __restrict__ gsum,
                        const float* __restrict__ Wl, const float* __restrict__ bl,
                        float* __restrict__ out){
  __shared__ float xr[D];     // in pos space
  int b = blockIdx.x, c = threadIdx.x;
  float gs = gsum[b*APAD];
  float s = 0.0f;
  #pragma unroll
  for (int ch = 0; ch < SPLIT; ++ch) s += xpart[((size_t)b * SPLIT + ch) * D + c];
  xr[c] = gs > 0.0f ? s / gs : 0.0f;
  __syncthreads();
  float a = bl[c];
  #pragma unroll 4
  for (int j = 0; j < D; ++j){
    float xv = xr[((j & 15) << 3) + (j >> 4)];   // pos = (col&15)*8 + (col>>4)
    a += xv * Wl[j*D + c];
  }
  out[(size_t)b * D + c] = lrelu(a);
}

extern "C" void kernel_launch(void* const* d_in, const int* in_sizes, int n_in,
                              void* d_out, int out_size, void* d_ws, size_t ws_size,
                              hipStream_t stream){
  // setup_inputs order: nodes, edges, edge_index, u, batch, Wq, bq, Wk, bk, Wv, bv, Wl, bl
  const float* edges = (const float*)d_in[1];
  const int*   send  = (const int*)d_in[2];      // edge_index[0] = first NE ints
  const float* u     = (const float*)d_in[3];
  const int*   batch = (const int*)d_in[4];
  const float* Wq    = (const float*)d_in[5];
  const float* bq    = (const float*)d_in[6];
  const float* Wk    = (const float*)d_in[7];
  const float* bk    = (const float*)d_in[8];
  const float* Wv    = (const float*)d_in[9];
  const float* bv    = (const float*)d_in[10];
  const float* Wl    = (const float*)d_in[11];
  const float* bl    = (const float*)d_in[12];
  float* out = (float*)d_out;

  char* wsb = (char*)d_ws;
  size_t off = 0;
  auto alloc = [&](size_t bytes)->char*{
    char* p = wsb + off; off += (bytes + 255) & ~(size_t)255; return p;
  };
  float*    kT     = (float*)   alloc((size_t)NB * D * 4);
  float*    qu     = (float*)   alloc((size_t)NB * D * 4);
  float*    vu     = (float*)   alloc((size_t)NB * D * 4);
  unsigned* gmax   = (unsigned*)alloc((size_t)NB * APAD * 4);
  float*    gsum   = (float*)   alloc((size_t)NB * APAD * 4);
  unsigned* hist   = (unsigned*)alloc((size_t)NB * APAD * 4);
  unsigned* cursor = (unsigned*)alloc((size_t)NB * APAD * 4);
  unsigned* offs   = (unsigned*)alloc((size_t)(NB + 1) * 4);
  unsigned short* WqTb = (unsigned short*)alloc((size_t)D * D * 2);
  unsigned short* WvTb = (unsigned short*)alloc((size_t)D * D * 2);
  float*    xpart  = (float*)   alloc((size_t)NB * SPLIT * D * 4);
  float*    scores = (float*)   alloc((size_t)NE * 4);
  int*      ebArr  = (int*)     alloc((size_t)NE * 4);
  unsigned* perm   = (unsigned*)alloc((size_t)NE * 4);
  unsigned short* vprime = (unsigned short*)alloc((size_t)NE * D * 2);  // 128 MB
  (void)ws_size; (void)in_sizes; (void)n_in; (void)out_size;

  k_init   <<<1, 256, 0, stream>>>(gmax, gsum, hist);
  k_pre    <<<NB, D, 0, stream>>>(u, Wq, bq, Wk, bk, Wv, bv, kT, qu, vu);
  k_prew   <<<D, D, 0, stream>>>(Wq, Wv, WqTb, WvTb);
  k_main   <<<GMAIN, 256, 0, stream>>>(edges, send, batch, WqTb, WvTb, qu, vu, kT,
                                       scores, ebArr, vprime);
  k_stats  <<<256, 256, 0, stream>>>(scores, ebArr, gmax, hist);
  k_scan   <<<1, 256, 0, stream>>>(hist, offs, cursor);
  k_scatter<<<256, 256, 0, stream>>>(scores, ebArr, gmax, cursor, perm, gsum);
  k_accum2 <<<NB * SPLIT, 256, 0, stream>>>((const unsigned*)vprime, scores, gmax, offs, perm, xpart);
  k_final  <<<NB, D, 0, stream>>>(xpart, gsum, Wl, bl, out);
}

// Round 11
// 225.019 us; speedup vs baseline: 2.9900x; 1.0463x over previous
//
#include <hip/hip_runtime.h>

#define NE 500000
#define NB 256
#define D  128
#define NT 7813           // ceil(NE/64) 64-edge tiles (4 waves x 16 rows)
#define GMAIN 512         // grid for k_main (2 blocks/CU co-resident)
#define SPLIT 16          // chunks per graph in k_accum2
#define APAD 8            // stride (u32) so each atomic counter sits on its own 32B
#define SCHUNK 1954       // ceil(NE/256)

typedef __attribute__((ext_vector_type(8))) short bf16x8;
typedef __attribute__((ext_vector_type(4))) float f32x4;

__device__ __forceinline__ float lrelu(float x){ return x > 0.0f ? x : 0.01f * x; }

// f32 -> bf16 (round-to-nearest-even), header-free
__device__ __forceinline__ unsigned short f2bf(float f){
  unsigned u = __float_as_uint(f);
  unsigned rounding = 0x7fffu + ((u >> 16) & 1u);
  return (unsigned short)((u + rounding) >> 16);
}

// monotonic float<->uint encoding for atomicMax on signed floats
__device__ __forceinline__ unsigned encf(float f){
  unsigned u = __float_as_uint(f);
  return (u & 0x80000000u) ? ~u : (u | 0x80000000u);
}
__device__ __forceinline__ float decf(unsigned u){
  return (u & 0x80000000u) ? __uint_as_float(u & 0x7fffffffu) : __uint_as_float(~u);
}

__global__ void k_init(unsigned* gmax, float* gsum, unsigned* hist){
  int t = threadIdx.x;
  if (t < NB){ gmax[t*APAD] = 0u; gsum[t*APAD] = 0.0f; hist[t*APAD] = 0u; }
}

// k = lrelu(u@Wk + bk); qu = u@Wq[128:] + bq; vu = u@Wv[128:] + bv
__global__ void k_pre(const float* __restrict__ u,  const float* __restrict__ Wq,
                      const float* __restrict__ bq, const float* __restrict__ Wk,
                      const float* __restrict__ bk, const float* __restrict__ Wv,
                      const float* __restrict__ bv,
                      float* __restrict__ kT, float* __restrict__ qu, float* __restrict__ vu){
  __shared__ float us[D];
  int b = blockIdx.x, c = threadIdx.x;
  us[c] = u[b*D + c];
  __syncthreads();
  float ka = bk[c], qa = bq[c], va = bv[c];
  #pragma unroll 4
  for (int j = 0; j < D; ++j){
    float uv = us[j];
    ka += uv * Wk[j*D + c];
    qa += uv * Wq[(D + j)*D + c];
    va += uv * Wv[(D + j)*D + c];
  }
  kT[b*D + c] = lrelu(ka);
  qu[b*D + c] = qa;
  vu[b*D + c] = va;
}

// WqT/WvT[c][k] = bf16(W[k][c]) for k<128 (edge half of the weight)
__global__ void k_prew(const float* __restrict__ Wq, const float* __restrict__ Wv,
                       unsigned short* __restrict__ WqT, unsigned short* __restrict__ WvT){
  int c = blockIdx.x, k = threadIdx.x;
  WqT[c*D + k] = f2bf(Wq[k*D + c]);
  WvT[c*D + k] = f2bf(Wv[k*D + c]);
}

// weight tables -> LDS, 256B rows, 16B-chunk XOR swizzle (bank-conflict-free reads)
__device__ __forceinline__ void stage_weights(unsigned short* wt, const unsigned short* Wsrc,
                                              int tid, int nthr){
  const uint4* wsrc = (const uint4*)Wsrc;      // 128x128 bf16 = 2048 uint4
  for (int i = tid; i < 2048; i += nthr){
    int c = i >> 4, off = (i & 15) << 4;
    *(uint4*)((char*)wt + c*256 + (off ^ ((c & 7) << 4))) = wsrc[i];
  }
}

// Fused single pass over edges with T14 register prefetch. 64-edge LDS tiles
// (per-lane-contiguous 128B global reads -> bf16 -> swizzled LDS), both GEMMs per
// tile with LDS-resident weights:
//   scores[e] = lrelu(edges[e]@Wq[:128] + qu[eb]) . k[eb] / sqrt(128)
//   vprime[e][m*8+n] = bf16(lrelu(edges[e]@Wv[:128] + vu[eb]))[col=16n+m]
__global__ __launch_bounds__(256, 2)
void k_main(const float* __restrict__ edges, const int* __restrict__ send,
            const int* __restrict__ batch, const unsigned short* __restrict__ WqT,
            const unsigned short* __restrict__ WvT, const float* __restrict__ qu,
            const float* __restrict__ vu, const float* __restrict__ kT,
            float* __restrict__ scores, int* __restrict__ ebArr,
            unsigned short* __restrict__ vprime){
  __shared__ __align__(16) unsigned short wq[D * D];   // 32 KB
  __shared__ __align__(16) unsigned short wv[D * D];   // 32 KB
  __shared__ __align__(16) unsigned short xs[64 * D];  // 16 KB  (total 80 KB)

  const int tid = threadIdx.x;
  stage_weights(wq, WqT, tid, 256);
  stage_weights(wv, WvT, tid, 256);

  const int lane = tid & 63, w = tid >> 6;
  const int g = lane >> 4, m = lane & 15;
  const int r = tid >> 2, q = tid & 3;   // staging: 4 threads/row, 128B contiguous each

  // ---- prologue prefetch: tile t0's edge rows + graph ids ----
  f32x4 pf[8];
  int ebm = 0;
  {
    long e = (long)blockIdx.x * 64 + r; long ec = e < NE ? e : NE - 1;
    const f32x4* src = (const f32x4*)(edges + (size_t)ec * D + q * 32);
    #pragma unroll
    for (int i = 0; i < 8; ++i) pf[i] = src[i];
    if (lane < 16){
      long eb_ = (long)blockIdx.x * 64 + w*16 + lane;
      long ebc = eb_ < NE ? eb_ : NE - 1;
      ebm = batch[send[ebc]];
    }
  }

  for (long tb = blockIdx.x; tb < NT; tb += GMAIN){
    const long rowbase = tb * 64;
    // write current tile to LDS (consumes prefetched pf)
    {
      char* xrow = (char*)xs + r * 256;
      #pragma unroll
      for (int ci = 0; ci < 4; ++ci){
        f32x4 a = pf[2*ci], b = pf[2*ci + 1];
        bf16x8 pk;
        pk[0] = (short)f2bf(a[0]); pk[1] = (short)f2bf(a[1]);
        pk[2] = (short)f2bf(a[2]); pk[3] = (short)f2bf(a[3]);
        pk[4] = (short)f2bf(b[0]); pk[5] = (short)f2bf(b[1]);
        pk[6] = (short)f2bf(b[2]); pk[7] = (short)f2bf(b[3]);
        int off = q * 64 + ci * 16;
        *(bf16x8*)(xrow + (off ^ ((r & 7) << 4))) = pk;
      }
    }
    int ebj[4];
    #pragma unroll
    for (int j = 0; j < 4; ++j) ebj[j] = __shfl(ebm, 4*g + j);
    if (lane < 16){
      long e = rowbase + w*16 + lane;
      if (e < NE) ebArr[e] = ebm;
    }
    __syncthreads();   // xs + (first iter) weights ready

    // A-fragments for my 16 rows
    const int arow = w*16 + m;
    bf16x8 af[4];
    #pragma unroll
    for (int ks = 0; ks < 4; ++ks)
      af[ks] = *(const bf16x8*)((const char*)xs + arow*256 + ((ks*64 + (g<<4)) ^ ((arow & 7) << 4)));

    // ---- issue next tile's prefetch (overlaps both GEMMs + epilogues) ----
    long tn = tb + GMAIN;
    if (tn < NT){
      long e = tn * 64 + r; long ec = e < NE ? e : NE - 1;
      const f32x4* src = (const f32x4*)(edges + (size_t)ec * D + q * 32);
      #pragma unroll
      for (int i = 0; i < 8; ++i) pf[i] = src[i];
      if (lane < 16){
        long eb_ = tn * 64 + w*16 + lane;
        long ebc = eb_ < NE ? eb_ : NE - 1;
        ebm = batch[send[ebc]];
      }
    }

    // ---- q-GEMM ----
    f32x4 acc[8];
    #pragma unroll
    for (int n = 0; n < 8; ++n)
      #pragma unroll
      for (int j = 0; j < 4; ++j) acc[n][j] = 0.0f;
    #pragma unroll
    for (int ks = 0; ks < 4; ++ks){
      int koff = ks*64 + (g << 4);
      #pragma unroll
      for (int n = 0; n < 8; ++n){
        int bc = 16*n + m, boff = koff ^ ((bc & 7) << 4);
        bf16x8 bqf = *(const bf16x8*)((const char*)wq + bc*256 + boff);
        acc[n] = __builtin_amdgcn_mfma_f32_16x16x32_bf16(af[ks], bqf, acc[n], 0, 0, 0);
      }
    }
    // q-epilogue: bias, dot with k[eb], reduce over m-bits
    #pragma unroll
    for (int j = 0; j < 4; ++j){
      long e = rowbase + w*16 + 4*g + j;
      const float* qrow = qu + (size_t)ebj[j] * D;
      const float* krow = kT + (size_t)ebj[j] * D;
      float p = 0.0f;
      #pragma unroll
      for (int n = 0; n < 8; ++n)
        p += lrelu(acc[n][j] + qrow[16*n + m]) * krow[16*n + m];
      p += __shfl_xor(p, 1); p += __shfl_xor(p, 2);
      p += __shfl_xor(p, 4); p += __shfl_xor(p, 8);
      if (m == 0 && e < NE) scores[e] = p * 0.08838834764831843f; // 1/sqrt(128)
    }

    // ---- v-GEMM (reuses acc) ----
    #pragma unroll
    for (int n = 0; n < 8; ++n)
      #pragma unroll
      for (int j = 0; j < 4; ++j) acc[n][j] = 0.0f;
    #pragma unroll
    for (int ks = 0; ks < 4; ++ks){
      int koff = ks*64 + (g << 4);
      #pragma unroll
      for (int n = 0; n < 8; ++n){
        int bc = 16*n + m, boff = koff ^ ((bc & 7) << 4);
        bf16x8 bvf = *(const bf16x8*)((const char*)wv + bc*256 + boff);
        acc[n] = __builtin_amdgcn_mfma_f32_16x16x32_bf16(af[ks], bvf, acc[n], 0, 0, 0);
      }
    }
    // v-epilogue: bias + lrelu + bf16 pack, 16B coalesced store
    #pragma unroll
    for (int j = 0; j < 4; ++j){
      long e = rowbase + w*16 + 4*g + j;
      const float* vrow = vu + (size_t)ebj[j] * D;
      bf16x8 pk;
      #pragma unroll
      for (int n = 0; n < 8; ++n)
        pk[n] = (short)f2bf(lrelu(acc[n][j] + vrow[16*n + m]));
      if (e < NE) *(bf16x8*)(vprime + (size_t)e * D + m*8) = pk;
    }
    __syncthreads();   // xs fully consumed before next stage
  }
}

// per-graph max + count (LDS pre-aggregation)
__global__ __launch_bounds__(256)
void k_stats(const float* __restrict__ scores, const int* __restrict__ ebArr,
             unsigned* gmax, unsigned* hist){
  __shared__ unsigned lmax[NB];
  __shared__ unsigned lcnt[NB];
  int tid = threadIdx.x;
  lmax[tid] = 0u; lcnt[tid] = 0u;
  __syncthreads();
  int start = blockIdx.x * SCHUNK;
  int end = start + SCHUNK; if (end > NE) end = NE;
  for (int e = start + tid; e < end; e += 256){
    int b = ebArr[e];
    atomicMax(&lmax[b], encf(scores[e]));
    atomicAdd(&lcnt[b], 1u);
  }
  __syncthreads();
  unsigned c = lcnt[tid];
  if (c){ atomicAdd(&hist[tid*APAD], c); atomicMax(&gmax[tid*APAD], lmax[tid]); }
}

__global__ void k_scan(const unsigned* __restrict__ hist, unsigned* __restrict__ offs,
                       unsigned* cursor){
  __shared__ unsigned sh[NB];
  __shared__ unsigned so[NB + 1];
  int tid = threadIdx.x;
  sh[tid] = hist[tid*APAD];
  __syncthreads();
  if (tid == 0){
    unsigned run = 0;
    for (int b = 0; b < NB; ++b){ so[b] = run; run += sh[b]; }
    so[NB] = run;
  }
  __syncthreads();
  offs[tid] = so[tid];
  cursor[tid*APAD] = so[tid];
  if (tid == 0) offs[NB] = so[NB];
}

// counting-sort scatter (block-batched) + per-graph sum of exp(score - max)
__global__ __launch_bounds__(256)
void k_scatter(const float* __restrict__ scores, const int* __restrict__ ebArr,
               const unsigned* __restrict__ gmax, unsigned* cursor,
               unsigned* __restrict__ perm, float* gsum){
  __shared__ unsigned lbase[NB];
  __shared__ unsigned lcnt[NB];
  __shared__ float lsum[NB];
  __shared__ float lgm[NB];
  int tid = threadIdx.x;
  lcnt[tid] = 0u; lsum[tid] = 0.0f; lgm[tid] = decf(gmax[tid*APAD]);
  __syncthreads();
  int start = blockIdx.x * SCHUNK;
  int end = start + SCHUNK; if (end > NE) end = NE;
  for (int e = start + tid; e < end; e += 256)
    atomicAdd(&lcnt[ebArr[e]], 1u);
  __syncthreads();
  unsigned c = lcnt[tid];
  lbase[tid] = c ? atomicAdd(&cursor[tid*APAD], c) : 0u;
  lcnt[tid] = 0u;
  __syncthreads();
  for (int e = start + tid; e < end; e += 256){
    int b = ebArr[e];
    unsigned p = lbase[b] + atomicAdd(&lcnt[b], 1u);
    perm[p] = (unsigned)e;
    atomicAdd(&lsum[b], __expf(scores[e] - lgm[b]));
  }
  __syncthreads();
  if (lsum[tid] != 0.0f) atomicAdd(&gsum[tid*APAD], lsum[tid]);
}

// per-(graph,chunk): weighted sum of bf16 v' rows (no GEMM) -> xpart in pos space
__global__ __launch_bounds__(256)
void k_accum2(const unsigned* __restrict__ vp32, const float* __restrict__ scores,
              const unsigned* __restrict__ gmax, const unsigned* __restrict__ offs,
              const unsigned* __restrict__ perm, float* __restrict__ xpart){
  __shared__ float xred[4 * D];
  const int tid = threadIdx.x;
  const int b = blockIdx.x >> 4, chunk = blockIdx.x & (SPLIT - 1);
  const unsigned o0 = offs[b];
  const int count = (int)(offs[b + 1] - o0);
  const int r0 = (int)(((long)count * chunk) / SPLIT);
  const int r1 = (int)(((long)count * (chunk + 1)) / SPLIT);
  const float gm = decf(gmax[b*APAD]);
  const int lane = tid & 63, w = tid >> 6;
  float xa = 0.0f, xb = 0.0f;
  #pragma unroll 4
  for (int i = r0 + w; i < r1; i += 4){
    unsigned e = perm[o0 + i];                       // wave-broadcast load
    float we = __expf(scores[e] - gm);
    unsigned d = vp32[(size_t)e * 64 + lane];        // 256B coalesced row
    xa += we * __uint_as_float(d << 16);
    xb += we * __uint_as_float(d & 0xffff0000u);
  }
  xred[w * D + 2*lane]     = xa;
  xred[w * D + 2*lane + 1] = xb;
  __syncthreads();
  if (tid < D){
    float s = xred[tid] + xred[D + tid] + xred[2*D + tid] + xred[3*D + tid];
    xpart[((size_t)b * SPLIT + chunk) * D + tid] = s;
  }
}

// sum chunks, /gsum, unpermute pos->col, then x@Wl + bl with lrelu
__global__ void k_final(const float* __restrict__ xpart, const float* __restrict__ gsum,
                        const float* __restrict__ Wl, const float* __restrict__ bl,
                        float* __restrict__ out){
  __shared__ float xr[D];     // in pos space
  int b = blockIdx.x, c = threadIdx.x;
  float gs = gsum[b*APAD];
  float s = 0.0f;
  #pragma unroll
  for (int ch = 0; ch < SPLIT; ++ch) s += xpart[((size_t)b * SPLIT + ch) * D + c];
  xr[c] = gs > 0.0f ? s / gs : 0.0f;
  __syncthreads();
  float a = bl[c];
  #pragma unroll 4
  for (int j = 0; j < D; ++j){
    float xv = xr[((j & 15) << 3) + (j >> 4)];   // pos = (col&15)*8 + (col>>4)
    a += xv * Wl[j*D + c];
  }
  out[(size_t)b * D + c] = lrelu(a);
}

extern "C" void kernel_launch(void* const* d_in, const int* in_sizes, int n_in,
                              void* d_out, int out_size, void* d_ws, size_t ws_size,
                              hipStream_t stream){
  // setup_inputs order: nodes, edges, edge_index, u, batch, Wq, bq, Wk, bk, Wv, bv, Wl, bl
  const float* edges = (const float*)d_in[1];
  const int*   send  = (const int*)d_in[2];      // edge_index[0] = first NE ints
  const float* u     = (const float*)d_in[3];
  const int*   batch = (const int*)d_in[4];
  const float* Wq    = (const float*)d_in[5];
  const float* bq    = (const float*)d_in[6];
  const float* Wk    = (const float*)d_in[7];
  const float* bk    = (const float*)d_in[8];
  const float* Wv    = (const float*)d_in[9];
  const float* bv    = (const float*)d_in[10];
  const float* Wl    = (const float*)d_in[11];
  const float* bl    = (const float*)d_in[12];
  float* out = (float*)d_out;

  char* wsb = (char*)d_ws;
  size_t off = 0;
  auto alloc = [&](size_t bytes)->char*{
    char* p = wsb + off; off += (bytes + 255) & ~(size_t)255; return p;
  };
  float*    kT     = (float*)   alloc((size_t)NB * D * 4);
  float*    qu     = (float*)   alloc((size_t)NB * D * 4);
  float*    vu     = (float*)   alloc((size_t)NB * D * 4);
  unsigned* gmax   = (unsigned*)alloc((size_t)NB * APAD * 4);
  float*    gsum   = (float*)   alloc((size_t)NB * APAD * 4);
  unsigned* hist   = (unsigned*)alloc((size_t)NB * APAD * 4);
  unsigned* cursor = (unsigned*)alloc((size_t)NB * APAD * 4);
  unsigned* offs   = (unsigned*)alloc((size_t)(NB + 1) * 4);
  unsigned short* WqTb = (unsigned short*)alloc((size_t)D * D * 2);
  unsigned short* WvTb = (unsigned short*)alloc((size_t)D * D * 2);
  float*    xpart  = (float*)   alloc((size_t)NB * SPLIT * D * 4);
  float*    scores = (float*)   alloc((size_t)NE * 4);
  int*      ebArr  = (int*)     alloc((size_t)NE * 4);
  unsigned* perm   = (unsigned*)alloc((size_t)NE * 4);
  unsigned short* vprime = (unsigned short*)alloc((size_t)NE * D * 2);  // 128 MB
  (void)ws_size; (void)in_sizes; (void)n_in; (void)out_size;

  k_init   <<<1, 256, 0, stream>>>(gmax, gsum, hist);
  k_pre    <<<NB, D, 0, stream>>>(u, Wq, bq, Wk, bk, Wv, bv, kT, qu, vu);
  k_prew   <<<D, D, 0, stream>>>(Wq, Wv, WqTb, WvTb);
  k_main   <<<GMAIN, 256, 0, stream>>>(edges, send, batch, WqTb, WvTb, qu, vu, kT,
                                       scores, ebArr, vprime);
  k_stats  <<<256, 256, 0, stream>>>(scores, ebArr, gmax, hist);
  k_scan   <<<1, 256, 0, stream>>>(hist, offs, cursor);
  k_scatter<<<256, 256, 0, stream>>>(scores, ebArr, gmax, cursor, perm, gsum);
  k_accum2 <<<NB * SPLIT, 256, 0, stream>>>((const unsigned*)vprime, scores, gmax, offs, perm, xpart);
  k_final  <<<NB, D, 0, stream>>>(xpart, gsum, Wl, bl, out);
}